// Round 13
// baseline (239.110 us; speedup 1.0000x reference)
//
#include <hip/hip_runtime.h>

#define NL 128          // N_LABELS
#define TT 512          // T
#define NB 512          // B
#define START_IDX 126
#define STOP_IDX 127

typedef __attribute__((ext_vector_type(8))) short bf16x8;
typedef __attribute__((ext_vector_type(4))) float f32x4;
typedef __attribute__((ext_vector_type(4))) unsigned u32x4;

__device__ __forceinline__ short f2bf(float x) {
    union { float f; unsigned u; } v; v.f = x;
    unsigned r = (v.u + 0x7FFFu + ((v.u >> 16) & 1u)) >> 16;  // RNE
    return (short)r;
}

__device__ __forceinline__ unsigned cvt_pk_bf16(float lo, float hi) {
    unsigned r;
    asm("v_cvt_pk_bf16_f32 %0, %1, %2" : "=v"(r) : "v"(lo), "v"(hi));
    return r;   // low half <- lo, high half <- hi
}

// LDS-only barrier: drain LDS ops (ds_write visibility) but NOT vmcnt — the
// in-flight global logits prefetches are lane-private and span barriers.
#define BAR() do {                                                            \
    asm volatile("s_waitcnt lgkmcnt(0)" ::: "memory");                        \
    __builtin_amdgcn_s_barrier();                                             \
} while (0)

#define MFMA16(A_, B_, C_) __builtin_amdgcn_mfma_f32_16x16x32_bf16(A_, B_, C_, 0, 0, 0)

// ---------------------------------------------------------------------------
// R13: 8 waves/block = TWO independent R10 pipelines in separate waves.
//   pipeline p = w>>2 (batches b0 = blk*32 + p*16), wave-within w4 = w&3.
// Per pipeline (identical to R10): 16 batches in MFMA columns; wave w4 owns
// m-tiles {w4, w4+4} = B word-group kk=w4 via phi; exchange = 1 ds_write_b128
// + 3 ds_read_b128 / step through its own stride-80 double-buffered LDS.
// Each SIMD hosts one A-wave + one B-wave -> mutual stall filling (the R10
// ~470cy/step stall is barrier skew + ds_read latency, wave-count-invariant;
// a second resident wave's MFMA/VALU issue hides it).
// el pipeline: 4 rotating raw pairs + 2 exp pairs (issue t+3, exp t+1 ahead).
// Lag-1 per-pipeline cross-wave max (pub t%4==2, cons t%4==3) -> exact 2^k
// rescale. Per-batch freeze at t==lenc via keep-old cndmask.
// ---------------------------------------------------------------------------
#define STEP(T_, PUB_, CONS_, EU_, EB_, RS_, RD_) do {                        \
    u32x4 bo_ = {bw0, bw1, bw2, bw3};                                         \
    bf16x8 bO_ = __builtin_bit_cast(bf16x8, bo_);                             \
    bf16x8 bA_ = __builtin_bit_cast(bf16x8, bvA);                             \
    bf16x8 bB_ = __builtin_bit_cast(bf16x8, bvB);                             \
    bf16x8 bC_ = __builtin_bit_cast(bf16x8, bvC);                             \
    f32x4 a0_ = {0.f,0.f,0.f,0.f}, a1_ = {0.f,0.f,0.f,0.f};                   \
    a0_ = MFMA16(afr[0][0], bO_, a0_);                                        \
    a1_ = MFMA16(afr[1][0], bO_, a1_);                                        \
    a0_ = MFMA16(afr[0][1], bA_, a0_);                                        \
    a1_ = MFMA16(afr[1][1], bA_, a1_);                                        \
    a0_ = MFMA16(afr[0][2], bB_, a0_);                                        \
    a1_ = MFMA16(afr[1][2], bB_, a1_);                                        \
    a0_ = MFMA16(afr[0][3], bC_, a0_);                                        \
    a1_ = MFMA16(afr[1][3], bC_, a1_);                                        \
    { int tp_ = (T_) + 3; if (tp_ > TT - 1) tp_ = TT - 1;                     \
      const float* lp_ = lsrc + (size_t)tp_ * NL;                             \
      RD_##A = *(const f32x4*)(lp_ + eo0);                                    \
      RD_##B = *(const f32x4*)(lp_ + eo1); }                                  \
    _Pragma("unroll")                                                         \
    for (int r_ = 0; r_ < 4; ++r_) {                                          \
        EB_##A[r_] = __expf(RS_##A[r_]);                                      \
        EB_##B[r_] = __expf(RS_##B[r_]);                                      \
    }                                                                         \
    float nv0_[4], nv1_[4];                                                   \
    _Pragma("unroll")                                                         \
    for (int r_ = 0; r_ < 4; ++r_) {                                          \
        nv0_[r_] = a0_[r_] * EU_##A[r_];                                      \
        nv1_[r_] = a1_[r_] * EU_##B[r_];                                      \
    }                                                                         \
    const bool live_ = (T_) < lenc;                                           \
    if (CONS_) {                                                              \
        float mx_ = fmaxf(fmaxf(smx[0][c], smx[1][c]),                        \
                          fmaxf(smx[2][c], smx[3][c]));                       \
        const unsigned eb_ = (__float_as_uint(mx_) >> 23) & 0xFFu;            \
        const float sc_ = __uint_as_float(((253u - eb_) & 0xFFu) << 23);      \
        _Pragma("unroll")                                                     \
        for (int r_ = 0; r_ < 4; ++r_) { nv0_[r_] *= sc_; nv1_[r_] *= sc_; }  \
        if (live_) cbi += (int)eb_ - 126;                                     \
    }                                                                         \
    if (PUB_) {                                                               \
        float lm_ = fmaxf(fmaxf(fmaxf(nv0_[0], nv0_[1]), fmaxf(nv0_[2], nv0_[3])), \
                          fmaxf(fmaxf(nv1_[0], nv1_[1]), fmaxf(nv1_[2], nv1_[3]))); \
        lm_ = fmaxf(lm_, __shfl_xor(lm_, 16));                                \
        lm_ = fmaxf(lm_, __shfl_xor(lm_, 32));                                \
        if (g == 0) smx[w4][c] = lm_;                                         \
    }                                                                         \
    { const unsigned n0_ = cvt_pk_bf16(nv0_[0], nv0_[1]);                     \
      const unsigned n1_ = cvt_pk_bf16(nv0_[2], nv0_[3]);                     \
      const unsigned n2_ = cvt_pk_bf16(nv1_[0], nv1_[1]);                     \
      const unsigned n3_ = cvt_pk_bf16(nv1_[2], nv1_[3]);                     \
      bw0 = live_ ? n0_ : bw0;  bw1 = live_ ? n1_ : bw1;                      \
      bw2 = live_ ? n2_ : bw2;  bw3 = live_ ? n3_ : bw3; }                    \
    char* nb_ = ((T_) & 1) ? sbuf0 : sbuf1;   /* buffer (T_+1)&1 */           \
    { u32x4 wv_ = {bw0, bw1, bw2, bw3};                                       \
      *(u32x4*)(nb_ + w4 * 1280 + slotOff) = wv_; }                           \
    BAR();                                                                    \
    bvA = *(const u32x4*)(nb_ + kA + slotOff);                                \
    bvB = *(const u32x4*)(nb_ + kB + slotOff);                                \
    bvC = *(const u32x4*)(nb_ + kC + slotOff);                                \
} while (0)

__global__ __launch_bounds__(512, 2)
void crf_scan(const float* __restrict__ logits,
              const int* __restrict__ lens,
              const float* __restrict__ trans,
              float* __restrict__ out)
{
    const int tid  = threadIdx.x;
    const int w    = tid >> 6;           // 0..7
    const int p    = w >> 2;             // pipeline 0/1
    const int w4   = w & 3;              // wave within pipeline
    const int lane = tid & 63;
    const int c    = lane & 15;          // batch / A row within tile / C col
    const int g    = lane >> 4;          // k-group

    const int base = blockIdx.x * 32;
    const int b0   = base + p * 16;

    // [pipe][buf][ kk*1280 + c*80 + g*16 ] (stride 80 -> conflict-light b128)
    __shared__ __align__(16) char sb[2][2][4 * 16 * 80];
    __shared__ float smax[2][4][16];

    char* sbuf0 = &sb[p][0][0];
    char* sbuf1 = &sb[p][1][0];
    float (*smx)[16] = smax[p];

    // ---- A fragments, chain-ordered: pos -> logical kk = (w4+pos)&3 ----
    bf16x8 afr[2][4];
    #pragma unroll
    for (int mi = 0; mi < 2; ++mi) {
        const int M = w4 + 4 * mi;
        const float* rowp = trans + (M * 16 + c) * NL + 4 * g;
        #pragma unroll
        for (int pos = 0; pos < 4; ++pos) {
            const int kk = (w4 + pos) & 3;
            f32x4 lo4 = *(const f32x4*)(rowp + kk * 16);        // j=0..3
            f32x4 hi4 = *(const f32x4*)(rowp + (kk + 4) * 16);  // j=4..7
            bf16x8 a;
            #pragma unroll
            for (int j = 0; j < 4; ++j) {
                a[j]     = f2bf(__expf(lo4[j]));
                a[j + 4] = f2bf(__expf(hi4[j]));
            }
            afr[mi][pos] = a;
        }
    }

    // own length + block-wide max over both pipelines' 32 batches
    int lenc = lens[b0 + c];
    lenc = lenc < 1 ? 1 : (lenc > TT ? TT : lenc);
    int lA = lens[base + c];
    int lB = lens[base + 16 + c];
    int gl = lA > lB ? lA : lB;
    gl = gl < 1 ? 1 : (gl > TT ? TT : gl);
    #pragma unroll
    for (int d = 1; d < 16; d <<= 1) { int o = __shfl_xor(gl, d); gl = gl > o ? gl : o; }
    const int glen = __builtin_amdgcn_readfirstlane(gl);

    const int slotOff = c * 80 + g * 16;
    const int kA = ((w4 + 1) & 3) * 1280;
    const int kB = ((w4 + 2) & 3) * 1280;
    const int kC = ((w4 + 3) & 3) * 1280;

    // ---- init: v0 one-hot at START(126) -> group kk=3, g=3, word 3, low half
    unsigned bw0 = 0u, bw1 = 0u, bw2 = 0u,
             bw3 = (w4 == 3 && g == 3) ? 0x00003F80u : 0u;
    { u32x4 z = {bw0, bw1, bw2, bw3};
      *(u32x4*)(sbuf0 + w4 * 1280 + slotOff) = z; }
    BAR();
    u32x4 bvA = *(const u32x4*)(sbuf0 + kA + slotOff);
    u32x4 bvB = *(const u32x4*)(sbuf0 + kB + slotOff);
    u32x4 bvC = *(const u32x4*)(sbuf0 + kC + slotOff);

    const float* lsrc = logits + (size_t)(b0 + c) * TT * NL;
    const int eo0 = w4 * 16 + 4 * g;         // labels of m-tile w4
    const int eo1 = (w4 + 4) * 16 + 4 * g;   // labels of m-tile w4+4

    // ---- el pipeline: 4 rotating raw pairs, 2 exp pairs ----
    f32x4 R0A, R0B, R1A, R1B, R2A, R2B, R3A, R3B;
    f32x4 E0A, E0B, E1A, E1B;
    R0A = *(const f32x4*)(lsrc + eo0);            R0B = *(const f32x4*)(lsrc + eo1);
    R1A = *(const f32x4*)(lsrc + NL + eo0);       R1B = *(const f32x4*)(lsrc + NL + eo1);
    R2A = *(const f32x4*)(lsrc + 2 * NL + eo0);   R2B = *(const f32x4*)(lsrc + 2 * NL + eo1);
    #pragma unroll
    for (int r = 0; r < 4; ++r) {
        E0A[r] = __expf(R0A[r]);  E0B[r] = __expf(R0B[r]);
    }

    int cbi = 0;
    int t = 0;
    const int tmain = glen & ~3;
    for (; t < tmain; t += 4) {
        STEP(t + 0, false, false, E0, E1, R1, R3);
        STEP(t + 1, false, false, E1, E0, R2, R0);
        STEP(t + 2, true,  false, E0, E1, R3, R1);
        STEP(t + 3, false, true,  E1, E0, R0, R2);
    }
    if (t < glen) { STEP(t, false, false, E0, E1, R1, R3); ++t; }
    if (t < glen) { STEP(t, false, false, E1, E0, R2, R0); ++t; }
    if (t < glen) { STEP(t, true,  false, E0, E1, R3, R1); ++t; }

    // ---- epilogue: wave w4==0 of each pipeline holds bw(0)+bvA(1)+bvB(2)+bvC(3)
    if (w4 == 0) {
        float s = 0.f;
        const float* stopr = trans + STOP_IDX * NL + 4 * g;
        u32x4 grp[4];
        grp[0] = (u32x4){bw0, bw1, bw2, bw3};
        grp[1] = bvA; grp[2] = bvB; grp[3] = bvC;
        #pragma unroll
        for (int kk = 0; kk < 4; ++kk) {
            f32x4 t0 = *(const f32x4*)(stopr + kk * 16);
            f32x4 t1 = *(const f32x4*)(stopr + (kk + 4) * 16);
            #pragma unroll
            for (int i = 0; i < 2; ++i) {
                const unsigned wd = grp[kk][i];
                s += __uint_as_float(wd << 16)         * __expf(t0[2 * i]);
                s += __uint_as_float(wd & 0xFFFF0000u) * __expf(t0[2 * i + 1]);
            }
            #pragma unroll
            for (int i = 2; i < 4; ++i) {
                const unsigned wd = grp[kk][i];
                s += __uint_as_float(wd << 16)         * __expf(t1[2 * (i - 2)]);
                s += __uint_as_float(wd & 0xFFFF0000u) * __expf(t1[2 * (i - 2) + 1]);
            }
        }
        s += __shfl_xor(s, 16);
        s += __shfl_xor(s, 32);
        if (g == 0)
            out[b0 + c] = (float)cbi * 0.69314718055994531f + __logf(s);
    }
}

extern "C" void kernel_launch(void* const* d_in, const int* in_sizes, int n_in,
                              void* d_out, int out_size, void* d_ws, size_t ws_size,
                              hipStream_t stream) {
    const float* logits = (const float*)d_in[0];
    const int*   lens   = (const int*)d_in[1];
    const float* trans  = (const float*)d_in[2];
    float*       outp   = (float*)d_out;
    crf_scan<<<NB / 32, 512, 0, stream>>>(logits, lens, trans, outp);
}

// Round 14
// 154.761 us; speedup vs baseline: 1.5450x; 1.5450x over previous
//
#include <hip/hip_runtime.h>

#define NL 128          // N_LABELS
#define TT 512          // T
#define NB 512          // B
#define START_IDX 126
#define STOP_IDX 127

typedef __attribute__((ext_vector_type(8))) short bf16x8;
typedef __attribute__((ext_vector_type(4))) float f32x4;
typedef __attribute__((ext_vector_type(4))) unsigned u32x4;

__device__ __forceinline__ short f2bf(float x) {
    union { float f; unsigned u; } v; v.f = x;
    unsigned r = (v.u + 0x7FFFu + ((v.u >> 16) & 1u)) >> 16;  // RNE
    return (short)r;
}

__device__ __forceinline__ unsigned cvt_pk_bf16(float lo, float hi) {
    unsigned r;
    asm("v_cvt_pk_bf16_f32 %0, %1, %2" : "=v"(r) : "v"(lo), "v"(hi));
    return r;   // low half <- lo, high half <- hi
}

// LDS-only barrier: drain LDS ops (ds_write visibility) but NOT vmcnt — the
// in-flight global logits prefetches are lane-private and span barriers.
#define BAR() do {                                                            \
    asm volatile("s_waitcnt lgkmcnt(0)" ::: "memory");                        \
    __builtin_amdgcn_s_barrier();                                             \
} while (0)

#define MFMA16(A_, B_, C_) __builtin_amdgcn_mfma_f32_16x16x32_bf16(A_, B_, C_, 0, 0, 0)

// ---------------------------------------------------------------------------
// R14 = R10 with the STEP re-sequenced to shorten the serial chain:
//   own MFMAs (no LDS dep) -> [cons: fold 2^k rescale into EU, off-tail]
//   -> issue loads(t+3) -> exp(EB)   [fills the ~120cy ds_read latency]
//   -> 6 read-dependent MFMAs -> nv -> pub -> cvt/freeze -> write -> BAR
//   -> reads for next step.
// Structure (identical to R10): one block = 16 batches (MFMA columns),
// 4 waves, wave w owns m-tiles {w, w+4} = B word-group kk=w via
// phi(kk*32+8g+j) = (kk+4*(j>>2))*16+4g+(j&3); exchange = 1 ds_write_b128 +
// 3 ds_read_b128 per step through stride-80 double-buffered LDS.
// el pipeline: 4 rotating raw pairs + 2 exp pairs (issue t+3, exp t+1 ahead).
// Lag-1 cross-wave max (pub t%4==2, cons t%4==3) -> exact 2^k rescale.
// Per-batch freeze at t==lenc via keep-old cndmask.
// ---------------------------------------------------------------------------
#define STEP(T_, PUB_, CONS_, EU_, EB_, RS_, RD_) do {                        \
    u32x4 bo_ = {bw0, bw1, bw2, bw3};                                         \
    bf16x8 bO_ = __builtin_bit_cast(bf16x8, bo_);                             \
    bf16x8 bA_ = __builtin_bit_cast(bf16x8, bvA);                             \
    bf16x8 bB_ = __builtin_bit_cast(bf16x8, bvB);                             \
    bf16x8 bC_ = __builtin_bit_cast(bf16x8, bvC);                             \
    f32x4 a0_ = {0.f,0.f,0.f,0.f}, a1_ = {0.f,0.f,0.f,0.f};                   \
    a0_ = MFMA16(afr[0][0], bO_, a0_);      /* own group: no LDS dep */       \
    a1_ = MFMA16(afr[1][0], bO_, a1_);                                        \
    if (CONS_) {        /* rescale folded into EU, off the nv tail */         \
        float mx_ = fmaxf(fmaxf(smax[0][c], smax[1][c]),                      \
                          fmaxf(smax[2][c], smax[3][c]));                     \
        const unsigned eb_ = (__float_as_uint(mx_) >> 23) & 0xFFu;            \
        const float sc_ = __uint_as_float(((253u - eb_) & 0xFFu) << 23);      \
        _Pragma("unroll")                                                     \
        for (int r_ = 0; r_ < 4; ++r_) {                                      \
            EU_##A[r_] *= sc_;  EU_##B[r_] *= sc_;                            \
        }                                                                     \
        if ((T_) < lenc) cbi += (int)eb_ - 126;                               \
    }                                                                         \
    { int tp_ = (T_) + 3; if (tp_ > TT - 1) tp_ = TT - 1;                     \
      const float* lp_ = lsrc + (size_t)tp_ * NL;                             \
      RD_##A = *(const f32x4*)(lp_ + eo0);                                    \
      RD_##B = *(const f32x4*)(lp_ + eo1); }                                  \
    _Pragma("unroll")   /* exp fills the ds_read latency window */            \
    for (int r_ = 0; r_ < 4; ++r_) {                                          \
        EB_##A[r_] = __expf(RS_##A[r_]);                                      \
        EB_##B[r_] = __expf(RS_##B[r_]);                                      \
    }                                                                         \
    a0_ = MFMA16(afr[0][1], bA_, a0_);                                        \
    a1_ = MFMA16(afr[1][1], bA_, a1_);                                        \
    a0_ = MFMA16(afr[0][2], bB_, a0_);                                        \
    a1_ = MFMA16(afr[1][2], bB_, a1_);                                        \
    a0_ = MFMA16(afr[0][3], bC_, a0_);                                        \
    a1_ = MFMA16(afr[1][3], bC_, a1_);                                        \
    float nv0_[4], nv1_[4];                                                   \
    _Pragma("unroll")                                                         \
    for (int r_ = 0; r_ < 4; ++r_) {                                          \
        nv0_[r_] = a0_[r_] * EU_##A[r_];                                      \
        nv1_[r_] = a1_[r_] * EU_##B[r_];                                      \
    }                                                                         \
    const bool live_ = (T_) < lenc;                                           \
    if (PUB_) {                                                               \
        float lm_ = fmaxf(fmaxf(fmaxf(nv0_[0], nv0_[1]), fmaxf(nv0_[2], nv0_[3])), \
                          fmaxf(fmaxf(nv1_[0], nv1_[1]), fmaxf(nv1_[2], nv1_[3]))); \
        lm_ = fmaxf(lm_, __shfl_xor(lm_, 16));                                \
        lm_ = fmaxf(lm_, __shfl_xor(lm_, 32));                                \
        if (g == 0) smax[w][c] = lm_;                                         \
    }                                                                         \
    { const unsigned n0_ = cvt_pk_bf16(nv0_[0], nv0_[1]);                     \
      const unsigned n1_ = cvt_pk_bf16(nv0_[2], nv0_[3]);                     \
      const unsigned n2_ = cvt_pk_bf16(nv1_[0], nv1_[1]);                     \
      const unsigned n3_ = cvt_pk_bf16(nv1_[2], nv1_[3]);                     \
      bw0 = live_ ? n0_ : bw0;  bw1 = live_ ? n1_ : bw1;                      \
      bw2 = live_ ? n2_ : bw2;  bw3 = live_ ? n3_ : bw3; }                    \
    char* nb_ = sb[((T_) + 1) & 1];                                           \
    { u32x4 wv_ = {bw0, bw1, bw2, bw3};                                       \
      *(u32x4*)(nb_ + w * 1280 + slotOff) = wv_; }                            \
    BAR();                                                                    \
    bvA = *(const u32x4*)(nb_ + kA + slotOff);                                \
    bvB = *(const u32x4*)(nb_ + kB + slotOff);                                \
    bvC = *(const u32x4*)(nb_ + kC + slotOff);                                \
} while (0)

__global__ __launch_bounds__(256)
void crf_scan(const float* __restrict__ logits,
              const int* __restrict__ lens,
              const float* __restrict__ trans,
              float* __restrict__ out)
{
    const int b0   = blockIdx.x * 16;
    const int tid  = threadIdx.x;
    const int w    = tid >> 6;           // wave: owns m-tiles {w, w+4} = group kk=w
    const int lane = tid & 63;
    const int c    = lane & 15;          // batch / A row within tile / C col
    const int g    = lane >> 4;          // k-group

    // slot(kk,c,g) = kk*1280 + c*80 + g*16 (stride 80 -> conflict-light b128)
    __shared__ __align__(16) char sb[2][4 * 16 * 80];
    __shared__ float smax[4][16];

    // ---- A fragments, chain-ordered: pos -> logical kk = (w+pos)&3 ----
    bf16x8 afr[2][4];
    #pragma unroll
    for (int mi = 0; mi < 2; ++mi) {
        const int M = w + 4 * mi;
        const float* rowp = trans + (M * 16 + c) * NL + 4 * g;
        #pragma unroll
        for (int pos = 0; pos < 4; ++pos) {
            const int kk = (w + pos) & 3;
            f32x4 lo4 = *(const f32x4*)(rowp + kk * 16);        // j=0..3
            f32x4 hi4 = *(const f32x4*)(rowp + (kk + 4) * 16);  // j=4..7
            bf16x8 a;
            #pragma unroll
            for (int j = 0; j < 4; ++j) {
                a[j]     = f2bf(__expf(lo4[j]));
                a[j + 4] = f2bf(__expf(hi4[j]));
            }
            afr[mi][pos] = a;
        }
    }

    int lenc = lens[b0 + c];
    lenc = lenc < 1 ? 1 : (lenc > TT ? TT : lenc);
    int gl = lenc;
    #pragma unroll
    for (int d = 1; d < 16; d <<= 1) { int o = __shfl_xor(gl, d); gl = gl > o ? gl : o; }
    const int glen = __builtin_amdgcn_readfirstlane(gl);

    const int slotOff = c * 80 + g * 16;
    const int kA = ((w + 1) & 3) * 1280;
    const int kB = ((w + 2) & 3) * 1280;
    const int kC = ((w + 3) & 3) * 1280;

    // ---- init: v0 one-hot at START(126) -> group kk=3, g=3, word 3, low half
    unsigned bw0 = 0u, bw1 = 0u, bw2 = 0u,
             bw3 = (w == 3 && g == 3) ? 0x00003F80u : 0u;
    { u32x4 z = {bw0, bw1, bw2, bw3};
      *(u32x4*)(sb[0] + w * 1280 + slotOff) = z; }
    BAR();
    u32x4 bvA = *(const u32x4*)(sb[0] + kA + slotOff);
    u32x4 bvB = *(const u32x4*)(sb[0] + kB + slotOff);
    u32x4 bvC = *(const u32x4*)(sb[0] + kC + slotOff);

    const float* lsrc = logits + (size_t)(b0 + c) * TT * NL;
    const int eo0 = w * 16 + 4 * g;          // labels of m-tile w
    const int eo1 = (w + 4) * 16 + 4 * g;    // labels of m-tile w+4

    // ---- el pipeline: 4 rotating raw pairs, 2 exp pairs ----
    f32x4 R0A, R0B, R1A, R1B, R2A, R2B, R3A, R3B;
    f32x4 E0A, E0B, E1A, E1B;
    R0A = *(const f32x4*)(lsrc + eo0);            R0B = *(const f32x4*)(lsrc + eo1);
    R1A = *(const f32x4*)(lsrc + NL + eo0);       R1B = *(const f32x4*)(lsrc + NL + eo1);
    R2A = *(const f32x4*)(lsrc + 2 * NL + eo0);   R2B = *(const f32x4*)(lsrc + 2 * NL + eo1);
    #pragma unroll
    for (int r = 0; r < 4; ++r) {
        E0A[r] = __expf(R0A[r]);  E0B[r] = __expf(R0B[r]);
    }

    int cbi = 0;
    int t = 0;
    const int tmain = glen & ~3;
    for (; t < tmain; t += 4) {
        STEP(t + 0, false, false, E0, E1, R1, R3);
        STEP(t + 1, false, false, E1, E0, R2, R0);
        STEP(t + 2, true,  false, E0, E1, R3, R1);
        STEP(t + 3, false, true,  E1, E0, R0, R2);
    }
    if (t < glen) { STEP(t, false, false, E0, E1, R1, R3); ++t; }
    if (t < glen) { STEP(t, false, false, E1, E0, R2, R0); ++t; }
    if (t < glen) { STEP(t, true,  false, E0, E1, R3, R1); ++t; }

    // ---- epilogue (wave 0): final B-groups are bw(kk=0) + bvA/bvB/bvC (1,2,3)
    if (w == 0) {
        float s = 0.f;
        const float* stopr = trans + STOP_IDX * NL + 4 * g;
        u32x4 grp[4];
        grp[0] = (u32x4){bw0, bw1, bw2, bw3};
        grp[1] = bvA; grp[2] = bvB; grp[3] = bvC;
        #pragma unroll
        for (int kk = 0; kk < 4; ++kk) {
            f32x4 t0 = *(const f32x4*)(stopr + kk * 16);
            f32x4 t1 = *(const f32x4*)(stopr + (kk + 4) * 16);
            #pragma unroll
            for (int i = 0; i < 2; ++i) {
                const unsigned wd = grp[kk][i];
                s += __uint_as_float(wd << 16)         * __expf(t0[2 * i]);
                s += __uint_as_float(wd & 0xFFFF0000u) * __expf(t0[2 * i + 1]);
            }
            #pragma unroll
            for (int i = 2; i < 4; ++i) {
                const unsigned wd = grp[kk][i];
                s += __uint_as_float(wd << 16)         * __expf(t1[2 * (i - 2)]);
                s += __uint_as_float(wd & 0xFFFF0000u) * __expf(t1[2 * (i - 2) + 1]);
            }
        }
        s += __shfl_xor(s, 16);
        s += __shfl_xor(s, 32);
        if (g == 0)
            out[b0 + c] = (float)cbi * 0.69314718055994531f + __logf(s);
    }
}

extern "C" void kernel_launch(void* const* d_in, const int* in_sizes, int n_in,
                              void* d_out, int out_size, void* d_ws, size_t ws_size,
                              hipStream_t stream) {
    const float* logits = (const float*)d_in[0];
    const int*   lens   = (const int*)d_in[1];
    const float* trans  = (const float*)d_in[2];
    float*       outp   = (float*)d_out;
    crf_scan<<<NB / 16, 256, 0, stream>>>(logits, lens, trans, outp);
}